// Round 20
// baseline (503.732 us; speedup 1.0000x reference)
//
#include <hip/hip_runtime.h>
#include <math.h>

#define TPB 256

typedef short s16x8 __attribute__((ext_vector_type(8)));
typedef short s16x4 __attribute__((ext_vector_type(4)));
typedef float f32x4 __attribute__((ext_vector_type(4)));

__device__ inline void bsplit(float x, short& h, short& l){
  union { float f; unsigned u; } a, hf, rf;
  a.f = x;
  unsigned hu = (a.u + 0x7FFFu + ((a.u >> 16) & 1u)) >> 16;
  h = (short)hu;
  hf.u = hu << 16;
  rf.f = x - hf.f;
  l = (short)((rf.u + 0x7FFFu + ((rf.u >> 16) & 1u)) >> 16);
}
__device__ inline float b2f(short s){
  union { unsigned u; float f; } x;
  x.u = ((unsigned)(unsigned short)s) << 16;
  return x.f;
}

// ==== weight split + MFMA-native reorder ====
__global__ __launch_bounds__(TPB) void wsplit_k(
    const float* __restrict__ w, short* __restrict__ wh, short* __restrict__ wl,
    int C, int O, int ntap, int total)
{
  int idx = blockIdx.x*TPB + threadIdx.x;
  if (idx >= total) return;
  int c   = idx % C;
  int t2  = idx / C;
  int oc  = t2 % O;
  int tap = t2 / O;
  float x = w[((size_t)oc*C + c)*ntap + tap];
  short h, l; bsplit(x, h, l);
  int tile = oc >> 4, ln = oc & 15;
  int S    = ntap*(C >> 5);
  int sl   = tap*(C >> 5) + (c >> 5);
  int lg   = (c >> 3) & 3, j = c & 7;
  size_t dst = (((size_t)tile*S + sl)*64 + lg*16 + ln)*8 + j;
  wh[dst] = h; wl[dst] = l;
}

__global__ __launch_bounds__(TPB) void wsplit1_k(
    const float* __restrict__ w, short* __restrict__ wh, short* __restrict__ wl)
{
  int idx = blockIdx.x*TPB + threadIdx.x;
  if (idx >= 64*576) return;
  int k  = idx % 576;
  int oc = idx / 576;
  int g  = k >> 4, kw = k & 15;
  int c  = g / 12, kh = g % 12;
  float x = 0.f;
  if (kh < 11 && kw < 11)
    x = w[((size_t)oc*3 + c)*121 + kh*11 + kw];
  short h, l; bsplit(x, h, l);
  int m = oc >> 4, ln = oc & 15;
  int s = k >> 5, r = k & 31;
  int lg = r >> 3, j = r & 7;
  size_t dst = (((size_t)m*18 + s)*64 + lg*16 + ln)*8 + j;
  wh[dst] = h; wl[dst] = l;
}

__global__ __launch_bounds__(TPB) void wtrans_k(
    const float* __restrict__ w, float* __restrict__ wT, int K, int O)
{
  int idx = blockIdx.x*TPB + threadIdx.x;
  if (idx >= K*O) return;
  int oc = idx % O;
  int k  = idx / O;
  wT[idx] = w[(size_t)oc*K + k];
}

// ========= conv1+pool1 fused MFMA v2: ow-split halves for occupancy =========
#define CW1 128
__global__ __launch_bounds__(256, 4) void conv1p_k(
    const float* __restrict__ in, const short* __restrict__ whi,
    const short* __restrict__ wlo, const float* __restrict__ bias,
    short* __restrict__ yh, short* __restrict__ yl)
{
  __shared__ __align__(16) short lds[2][57*CW1 + 176];
  const int tid = threadIdx.x;
  const int r  = blockIdx.x;
  const int b  = blockIdx.y;
  const int hf = blockIdx.z;
  const int wid = tid >> 6;
  const int ntl = wid & 1;
  const int och = wid >> 1;
  const int ln = tid & 15;
  const int lg = (tid & 63) >> 4;
  const int lane = tid & 63;
  const int lw = ntl*16 + ln;
  const int iwbase = hf*112 - 2;

  const float* ip = in + (size_t)b*3*224*224;
  for (int i = tid; i < 57*32; i += 256){
    int plane = i >> 5;
    int p     = i & 31;
    int c = plane / 19, ri = plane % 19;
    int ih = 8*r - 2 + ri;
    int col0 = p*4;
    const float* rowp = (ih >= 0 && ih < 224) ? ip + (size_t)c*50176 + (size_t)ih*224 : nullptr;
    short h[4], l[4];
    #pragma unroll
    for (int j=0;j<4;++j){
      int iw = iwbase + col0 + j;
      float v = (rowp && iw >= 0 && iw < 224) ? rowp[iw] : 0.f;
      bsplit(v, h[j], l[j]);
    }
    s16x4 hv = {h[0],h[1],h[2],h[3]}, lv = {l[0],l[1],l[2],l[3]};
    *reinterpret_cast<s16x4*>(&lds[0][plane*CW1 + col0]) = hv;
    *reinterpret_cast<s16x4*>(&lds[1][plane*CW1 + col0]) = lv;
  }
  __syncthreads();

  f32x4 acc[3][2];
  #pragma unroll
  for (int m=0;m<2;++m){
    const float4 bv = *reinterpret_cast<const float4*>(bias + och*32 + m*16 + lg*4);
    #pragma unroll
    for (int sub=0;sub<3;++sub)
      acc[sub][m] = (f32x4){bv.x, bv.y, bv.z, bv.w};
  }

  s16x8 ah[2], al[2], ahn[2], aln[2];
  #pragma unroll
  for (int m=0;m<2;++m){
    size_t ao = (((size_t)(och*2+m)*18 + 0)*64 + lane)*8;
    ah[m] = *reinterpret_cast<const s16x8*>(whi + ao);
    al[m] = *reinterpret_cast<const s16x8*>(wlo + ao);
  }

  #pragma unroll 1
  for (int s=0; s<18; ++s){
    if (s < 17){
      #pragma unroll
      for (int m=0;m<2;++m){
        size_t ao = (((size_t)(och*2+m)*18 + s + 1)*64 + lane)*8;
        ahn[m] = *reinterpret_cast<const s16x8*>(whi + ao);
        aln[m] = *reinterpret_cast<const s16x8*>(wlo + ao);
      }
    }
    int g  = 2*s + (lg >> 1);
    int c  = g / 12, kh = g % 12;
    int khp = (kh < 11) ? kh : 10;
    #pragma unroll
    for (int sub=0;sub<3;++sub){
      int plane = c*19 + 4*sub + khp;
      int base  = plane*CW1 + lw*4 + (lg & 1)*8;
      s16x4 h0 = *reinterpret_cast<const s16x4*>(&lds[0][base]);
      s16x4 h1 = *reinterpret_cast<const s16x4*>(&lds[0][base+4]);
      s16x4 l0 = *reinterpret_cast<const s16x4*>(&lds[1][base]);
      s16x4 l1 = *reinterpret_cast<const s16x4*>(&lds[1][base+4]);
      s16x8 bh = __builtin_shufflevector(h0, h1, 0,1,2,3,4,5,6,7);
      s16x8 bl = __builtin_shufflevector(l0, l1, 0,1,2,3,4,5,6,7);
      #pragma unroll
      for (int m=0;m<2;++m){
        acc[sub][m] = __builtin_amdgcn_mfma_f32_16x16x32_bf16(al[m], bh, acc[sub][m], 0,0,0);
        acc[sub][m] = __builtin_amdgcn_mfma_f32_16x16x32_bf16(ah[m], bl, acc[sub][m], 0,0,0);
        acc[sub][m] = __builtin_amdgcn_mfma_f32_16x16x32_bf16(ah[m], bh, acc[sub][m], 0,0,0);
      }
    }
    #pragma unroll
    for (int m=0;m<2;++m){ ah[m] = ahn[m]; al[m] = aln[m]; }
  }

  __syncthreads();
  float* convbuf = (float*)&lds[0][0];
  #pragma unroll
  for (int sub=0;sub<3;++sub)
    #pragma unroll
    for (int m=0;m<2;++m)
      #pragma unroll
      for (int rr=0;rr<4;++rr){
        int oc = och*32 + m*16 + lg*4 + rr;
        convbuf[(sub*36 + lw)*65 + oc] = fmaxf(acc[sub][m][rr], 0.f);
      }
  __syncthreads();

  const int npw = hf ? 13 : 14;
  for (int i = tid; i < npw*64; i += 256){
    int pwl = i >> 6, c = i & 63;
    float m = -INFINITY;
    #pragma unroll
    for (int sub=0;sub<3;++sub)
      #pragma unroll
      for (int j=0;j<3;++j)
        m = fmaxf(m, convbuf[(sub*36 + 2*pwl + j)*65 + c]);
    short h, l; bsplit(m, h, l);
    int pw = hf*14 + pwl;
    size_t o = ((size_t)b*729 + r*27 + pw)*64 + c;
    yh[o] = h; yl[o] = l;
  }
}

// ============== conv2 MFMA v4: 128-thr blocks, oc split across grid ==========
// grid (9 rg, 64 b, 2 och) = 1152 blocks x 2 waves -> 4 blocks/CU (LDS),
// ~8 waves/CU steady; same math as v3 (wave = 48 ocs, 3Mx6N).
__global__ __launch_bounds__(128) void conv2m_k(
    const short* __restrict__ xh, const short* __restrict__ xl,
    const short* __restrict__ whi, const short* __restrict__ wlo,
    const float* __restrict__ bias, short* __restrict__ yh, short* __restrict__ yl)
{
  __shared__ __align__(16) short lds[2][217*40];
  const int tid = threadIdx.x;
  const int rg  = blockIdx.x;
  const int b   = blockIdx.y;
  const int och = blockIdx.z;
  const int wid = tid >> 6;          // 0..1
  const int ln  = tid & 15;
  const int lg  = (tid & 63) >> 4;
  const int lane = tid & 63;
  const int wt  = och*2 + wid;       // wave-tile 0..3 (48 ocs each)
  const int oc0 = wt*48;
  const int r0  = rg*3;

  int sb[6], nn[6];
  #pragma unroll
  for (int t=0;t<6;++t){
    int n = t*16 + ln;
    nn[t] = n;
    int ohl = n / 27, ow = n % 27;
    sb[t] = (n < 81) ? (ohl*31 + ow) : 0;
  }

  f32x4 acc[3][6];
  #pragma unroll
  for (int m=0;m<3;++m){
    const float4 bv = *reinterpret_cast<const float4*>(bias + oc0 + m*16 + lg*4);
    #pragma unroll
    for (int t=0;t<6;++t) acc[m][t] = (f32x4){bv.x, bv.y, bv.z, bv.w};
  }

  #pragma unroll 1
  for (int c0=0; c0<64; c0+=32){
    __syncthreads();
    for (int i = tid; i < 217*4; i += 128){
      int sp = i >> 2, v = i & 3;
      int pr = sp/31, pc = sp%31;
      int ih = r0 - 2 + pr, iw = pc - 2;
      s16x8 hv = {0,0,0,0,0,0,0,0}, lv = {0,0,0,0,0,0,0,0};
      if (ih >= 0 && ih < 27 && iw >= 0 && iw < 27){
        size_t o = ((size_t)b*729 + ih*27 + iw)*64 + c0 + v*8;
        hv = *reinterpret_cast<const s16x8*>(xh + o);
        lv = *reinterpret_cast<const s16x8*>(xl + o);
      }
      *reinterpret_cast<s16x8*>(&lds[0][sp*40 + v*8]) = hv;
      *reinterpret_cast<s16x8*>(&lds[1][sp*40 + v*8]) = lv;
    }
    __syncthreads();

    const size_t tstr = 50*512;
    const size_t abase = ((size_t)(wt*3)*50 + (c0 >> 5))*512 + (size_t)lane*8;
    s16x8 ah0 = *reinterpret_cast<const s16x8*>(whi + abase);
    s16x8 ah1 = *reinterpret_cast<const s16x8*>(whi + abase + tstr);
    s16x8 ah2 = *reinterpret_cast<const s16x8*>(whi + abase + 2*tstr);
    s16x8 al0 = *reinterpret_cast<const s16x8*>(wlo + abase);
    s16x8 al1 = *reinterpret_cast<const s16x8*>(wlo + abase + tstr);
    s16x8 al2 = *reinterpret_cast<const s16x8*>(wlo + abase + 2*tstr);

    #pragma unroll 1
    for (int tap=0; tap<25; ++tap){
      s16x8 nh0=ah0, nh1=ah1, nh2=ah2, nl0=al0, nl1=al1, nl2=al2;
      if (tap < 24){
        size_t ao = abase + (size_t)(tap+1)*2*512;
        nh0 = *reinterpret_cast<const s16x8*>(whi + ao);
        nh1 = *reinterpret_cast<const s16x8*>(whi + ao + tstr);
        nh2 = *reinterpret_cast<const s16x8*>(whi + ao + 2*tstr);
        nl0 = *reinterpret_cast<const s16x8*>(wlo + ao);
        nl1 = *reinterpret_cast<const s16x8*>(wlo + ao + tstr);
        nl2 = *reinterpret_cast<const s16x8*>(wlo + ao + 2*tstr);
      }
      const int toff = (tap/5)*31 + (tap%5);
      #pragma unroll
      for (int t=0;t<6;++t){
        int off = (sb[t] + toff)*40 + (c0 ? 0 : 0) + lg*8;
        s16x8 bh = *reinterpret_cast<const s16x8*>(&lds[0][off]);
        s16x8 bl = *reinterpret_cast<const s16x8*>(&lds[1][off]);
        acc[0][t] = __builtin_amdgcn_mfma_f32_16x16x32_bf16(al0, bh, acc[0][t], 0,0,0);
        acc[0][t] = __builtin_amdgcn_mfma_f32_16x16x32_bf16(ah0, bl, acc[0][t], 0,0,0);
        acc[0][t] = __builtin_amdgcn_mfma_f32_16x16x32_bf16(ah0, bh, acc[0][t], 0,0,0);
        acc[1][t] = __builtin_amdgcn_mfma_f32_16x16x32_bf16(al1, bh, acc[1][t], 0,0,0);
        acc[1][t] = __builtin_amdgcn_mfma_f32_16x16x32_bf16(ah1, bl, acc[1][t], 0,0,0);
        acc[1][t] = __builtin_amdgcn_mfma_f32_16x16x32_bf16(ah1, bh, acc[1][t], 0,0,0);
        acc[2][t] = __builtin_amdgcn_mfma_f32_16x16x32_bf16(al2, bh, acc[2][t], 0,0,0);
        acc[2][t] = __builtin_amdgcn_mfma_f32_16x16x32_bf16(ah2, bl, acc[2][t], 0,0,0);
        acc[2][t] = __builtin_amdgcn_mfma_f32_16x16x32_bf16(ah2, bh, acc[2][t], 0,0,0);
      }
      ah0=nh0; ah1=nh1; ah2=nh2; al0=nl0; al1=nl1; al2=nl2;
    }
  }

  #pragma unroll
  for (int m=0;m<3;++m)
    #pragma unroll
    for (int t=0;t<6;++t){
      if (nn[t] < 81){
        int gsp = r0*27 + nn[t];
        size_t base = ((size_t)b*729 + gsp)*192 + oc0 + m*16 + lg*4;
        short h[4], l[4];
        #pragma unroll
        for (int r=0;r<4;++r) bsplit(fmaxf(acc[m][t][r], 0.f), h[r], l[r]);
        s16x4 hv = {h[0],h[1],h[2],h[3]}, lv = {l[0],l[1],l[2],l[3]};
        *reinterpret_cast<s16x4*>(yh + base) = hv;
        *reinterpret_cast<s16x4*>(yl + base) = lv;
      }
    }
}

// ---- pool2: X3[729][192] split -> X4[169][192] split ----
__global__ __launch_bounds__(TPB) void pool2_k(
    const short* __restrict__ xh, const short* __restrict__ xl,
    short* __restrict__ yh, short* __restrict__ yl)
{
  int i = blockIdx.x*TPB + threadIdx.x;
  if (i >= 64*169*192) return;
  int c = i % 192;
  int t = i / 192;
  int sp = t % 169;
  int b = t / 169;
  int r = sp/13, cc = sp%13;
  const short* ph = xh + (size_t)b*729*192 + c;
  const short* pl = xl + (size_t)b*729*192 + c;
  float m = -INFINITY;
  #pragma unroll
  for (int di=0;di<3;++di)
    #pragma unroll
    for (int dj=0;dj<3;++dj){
      size_t s = (size_t)((2*r+di)*27 + 2*cc+dj)*192;
      m = fmaxf(m, b2f(ph[s]) + b2f(pl[s]));
    }
  short h, l; bsplit(m, h, l);
  yh[i] = h; yl[i] = l;
}

// ============== conv3/4/5 MFMA; in: split ch-minor [169][C]; out: [169][O] =====
template<int C,int O>
__global__ __launch_bounds__(256, 3) void conv3m_k(
    const short* __restrict__ xh, const short* __restrict__ xl,
    const short* __restrict__ whi, const short* __restrict__ wlo,
    const float* __restrict__ bias, short* __restrict__ yh, short* __restrict__ yl)
{
  __shared__ __align__(16) short lds[2][225*40];
  const int tid = threadIdx.x;
  const int b   = blockIdx.y;
  const int wid = tid >> 6;
  const int ln  = tid & 15;
  const int lg  = (tid & 63) >> 4;
  const int lane = tid & 63;
  const int tileIdx = blockIdx.x*2 + (wid & 1);
  const int oc0 = tileIdx*16;
  const int ng  = wid >> 1;
  const int tbase  = ng ? 6 : 0;
  const int ntiles = ng ? 5 : 6;
  const int S3 = 9*(C/32);

  int sb[6], nn[6];
  #pragma unroll
  for (int t=0;t<6;++t){
    int n = (tbase + t)*16 + ln;
    nn[t] = n;
    int oh = n / 13, ow = n % 13;
    sb[t] = (n < 169) ? (oh*15 + ow) : 0;
  }

  f32x4 acc[6];
  const float4 bv = *reinterpret_cast<const float4*>(bias + oc0 + lg*4);
  #pragma unroll
  for (int t=0;t<6;++t) acc[t] = (f32x4){bv.x, bv.y, bv.z, bv.w};

  #pragma unroll 1
  for (int c0=0; c0<C; c0+=32){
    __syncthreads();
    for (int i = tid; i < 225*4; i += 256){
      int sp = i >> 2, v = i & 3;
      int r = sp/15, cc = sp%15;
      s16x8 hv = {0,0,0,0,0,0,0,0}, lv = {0,0,0,0,0,0,0,0};
      if (r >= 1 && r <= 13 && cc >= 1 && cc <= 13){
        size_t o = ((size_t)b*169 + (r-1)*13 + (cc-1))*C + c0 + v*8;
        hv = *reinterpret_cast<const s16x8*>(xh + o);
        lv = *reinterpret_cast<const s16x8*>(xl + o);
      }
      *reinterpret_cast<s16x8*>(&lds[0][sp*40 + v*8]) = hv;
      *reinterpret_cast<s16x8*>(&lds[1][sp*40 + v*8]) = lv;
    }
    __syncthreads();

    const size_t tb = (size_t)tileIdx*S3 + (c0 >> 5);
    s16x8 ah = *reinterpret_cast<const s16x8*>(whi + (tb*64 + lane)*8);
    s16x8 al = *reinterpret_cast<const s16x8*>(wlo + (tb*64 + lane)*8);
    #pragma unroll 1
    for (int tap=0; tap<9; ++tap){
      s16x8 ahn = ah, aln = al;
      if (tap < 8){
        size_t ao = ((tb + (size_t)(tap+1)*(C/32))*64 + lane)*8;
        ahn = *reinterpret_cast<const s16x8*>(whi + ao);
        aln = *reinterpret_cast<const s16x8*>(wlo + ao);
      }
      const int toff = (tap/3)*15 + (tap%3);
      #pragma unroll
      for (int t=0;t<6;++t){
        if (t < ntiles){
          int off = (sb[t] + toff)*40 + lg*8;
          s16x8 bh = *reinterpret_cast<const s16x8*>(&lds[0][off]);
          s16x8 bl = *reinterpret_cast<const s16x8*>(&lds[1][off]);
          acc[t] = __builtin_amdgcn_mfma_f32_16x16x32_bf16(al, bh, acc[t], 0,0,0);
          acc[t] = __builtin_amdgcn_mfma_f32_16x16x32_bf16(ah, bl, acc[t], 0,0,0);
          acc[t] = __builtin_amdgcn_mfma_f32_16x16x32_bf16(ah, bh, acc[t], 0,0,0);
        }
      }
      ah = ahn; al = aln;
    }
  }

  #pragma unroll
  for (int t=0;t<6;++t){
    if (t < ntiles && nn[t] < 169){
      size_t base = ((size_t)b*169 + nn[t])*O + oc0 + lg*4;
      short h[4], l[4];
      #pragma unroll
      for (int r=0;r<4;++r) bsplit(fmaxf(acc[t][r], 0.f), h[r], l[r]);
      s16x4 hv = {h[0],h[1],h[2],h[3]}, lv = {l[0],l[1],l[2],l[3]};
      *reinterpret_cast<s16x4*>(yh + base) = hv;
      *reinterpret_cast<s16x4*>(yl + base) = lv;
    }
  }
}

// ---- pool3: X7[169][256] split -> feat[b][9216] f32 (d = c*36 + sp) ----
__global__ __launch_bounds__(TPB) void pool3_k(
    const short* __restrict__ xh, const short* __restrict__ xl,
    float* __restrict__ feat)
{
  int i = blockIdx.x*TPB + threadIdx.x;
  if (i >= 64*9216) return;
  int d = i % 9216;
  int b = i / 9216;
  int c = d / 36;
  int sp = d % 36;
  int r = sp/6, cc = sp%6;
  const short* ph = xh + (size_t)b*169*256 + c;
  const short* pl = xl + (size_t)b*169*256 + c;
  float m = -INFINITY;
  #pragma unroll
  for (int di=0;di<3;++di)
    #pragma unroll
    for (int dj=0;dj<3;++dj){
      size_t s = (size_t)((2*r+di)*13 + 2*cc+dj)*256;
      m = fmaxf(m, b2f(ph[s]) + b2f(pl[s]));
    }
  feat[i] = m;
}

// ---- featsplit: feat[b][9216] -> featBT B-native [288 s][4 nt][64 lane][8 j] ----
__global__ __launch_bounds__(TPB) void featsplit_k(
    const float* __restrict__ feat, short* __restrict__ fbh, short* __restrict__ fbl)
{
  int idx = blockIdx.x*TPB + threadIdx.x;
  if (idx >= 589824) return;
  int j = idx & 7;
  int lane = (idx >> 3) & 63;
  int nt = (idx >> 9) & 3;
  int s = idx >> 11;
  int b = nt*16 + (lane & 15);
  int d = s*32 + (lane >> 4)*8 + j;
  short h, l; bsplit(feat[(size_t)b*9216 + d], h, l);
  fbh[idx] = h; fbl[idx] = l;
}

// ---------------- gate ----------------
__global__ __launch_bounds__(256) void gate1_k(
    const float* __restrict__ feat, const float* __restrict__ gw1T,
    const float* __restrict__ gb1, float* __restrict__ g)
{
  const int b    = blockIdx.x;
  const int h    = blockIdx.y*4 + (threadIdx.x >> 6);
  const int lane = threadIdx.x & 63;
  const float* f = feat + (size_t)b*9216;
  const float* w = gw1T + (size_t)h*9216;
  float s = 0.f;
  #pragma unroll
  for (int it=0; it<36; ++it){
    int d = it*256 + lane*4;
    float4 fv = *reinterpret_cast<const float4*>(f + d);
    float4 wv = *reinterpret_cast<const float4*>(w + d);
    s = fmaf(fv.x, wv.x, s);
    s = fmaf(fv.y, wv.y, s);
    s = fmaf(fv.z, wv.z, s);
    s = fmaf(fv.w, wv.w, s);
  }
  #pragma unroll
  for (int off=32; off; off>>=1) s += __shfl_down(s, off, 64);
  if (lane == 0) g[(size_t)b*72 + h] = fmaxf(s + gb1[h], 0.f);
}

__global__ __launch_bounds__(128) void gate2_k(
    const float* __restrict__ g, const float* __restrict__ gw2,
    const float* __restrict__ gb2, float* __restrict__ gates)
{
  const int b = blockIdx.x;
  const int tid = threadIdx.x;
  __shared__ float gs[72];
  __shared__ float logits[8];
  if (tid < 72) gs[tid] = g[(size_t)b*72 + tid];
  __syncthreads();
  if (tid < 8) {
    float acc = gb2[tid];
    for (int j=0;j<72;++j)
      acc = fmaf(gs[j], gw2[(size_t)j*8 + tid], acc);
    logits[tid] = acc;
  }
  __syncthreads();
  if (tid == 0) {
    int i1 = 0; float v1 = logits[0];
    for (int e=1;e<8;++e) if (logits[e] > v1) { v1 = logits[e]; i1 = e; }
    int i2 = -1; float v2 = -INFINITY;
    for (int e=0;e<8;++e) { if (e==i1) continue; if (logits[e] > v2) { v2 = logits[e]; i2 = e; } }
    float z  = expf(v2 - v1);
    float w1 = 1.f / (1.f + z);
    float w2 = z   / (1.f + z);
    float* gr = gates + (size_t)b*8;
    for (int e=0;e<8;++e) gr[e] = 0.f;
    gr[i1] = w1;
    gr[i2] = w2;
  }
}

// ========== expert h1 MFMA streaming GEMM ==========
__global__ __launch_bounds__(256, 4) void eh1m_k(
    const float* __restrict__ ew1, const short* __restrict__ fbh,
    const short* __restrict__ fbl, float* __restrict__ part)
{
  __shared__ __align__(16) short wh_l[32*88];
  __shared__ __align__(16) short wl_l[32*88];
  const int m2 = blockIdx.x;
  const int e  = blockIdx.y;
  const int ks = blockIdx.z;
  const int tid = threadIdx.x;
  const int nt = tid >> 6;
  const int ln = tid & 15;
  const int lg = (tid & 63) >> 4;
  const int lane = tid & 63;

  f32x4 acc[2] = {(f32x4){0.f,0.f,0.f,0.f},(f32x4){0.f,0.f,0.f,0.f}};

  const float* wsrc = ew1 + (size_t)e*9216*288 + (size_t)m2*32;
  const int d0 = ks*576;

  #pragma unroll 1
  for (int st=0; st<9; ++st){
    __syncthreads();
    {
      int drow = tid >> 2;
      int h0 = (tid & 3)*8;
      const float* src = wsrc + (size_t)(d0 + st*64 + drow)*288 + h0;
      float4 v0 = *reinterpret_cast<const float4*>(src);
      float4 v1 = *reinterpret_cast<const float4*>(src+4);
      float vv[8] = {v0.x,v0.y,v0.z,v0.w,v1.x,v1.y,v1.z,v1.w};
      #pragma unroll
      for (int k=0;k<8;++k){
        short h, l; bsplit(vv[k], h, l);
        wh_l[(h0+k)*88 + drow] = h;
        wl_l[(h0+k)*88 + drow] = l;
      }
    }
    __syncthreads();
    int sg = (d0 + st*64) >> 5;
    #pragma unroll
    for (int sl=0; sl<2; ++sl){
      size_t bo = ((size_t)(sg+sl)*4 + nt)*512 + (size_t)lane*8;
      s16x8 bh = *reinterpret_cast<const s16x8*>(fbh + bo);
      s16x8 bl = *reinterpret_cast<const s16x8*>(fbl + bo);
      #pragma unroll
      for (int m=0;m<2;++m){
        int ao = (m*16 + ln)*88 + sl*32 + lg*8;
        s16x8 ah = *reinterpret_cast<const s16x8*>(&wh_l[ao]);
        s16x8 al = *reinterpret_cast<const s16x8*>(&wl_l[ao]);
        acc[m] = __builtin_amdgcn_mfma_f32_16x16x32_bf16(al, bh, acc[m], 0,0,0);
        acc[m] = __builtin_amdgcn_mfma_f32_16x16x32_bf16(ah, bl, acc[m], 0,0,0);
        acc[m] = __builtin_amdgcn_mfma_f32_16x16x32_bf16(ah, bh, acc[m], 0,0,0);
      }
    }
  }
  #pragma unroll
  for (int m=0;m<2;++m){
    int h = m2*32 + m*16 + lg*4;
    int b = nt*16 + ln;
    float* pp = part + ((size_t)(ks*8+e)*288 + h)*64 + b;
    #pragma unroll
    for (int r=0;r<4;++r)
      pp[(size_t)r*64] = acc[m][r];
  }
}

__global__ __launch_bounds__(TPB) void eh1_reduce_k(
    const float* __restrict__ part, const float* __restrict__ eb1,
    float* __restrict__ h1)
{
  int idx = blockIdx.x*TPB + threadIdx.x;
  if (idx >= 8*288*64) return;
  int b = idx & 63;
  int h = (idx >> 6) % 288;
  int e = idx / (64*288);
  float a = eb1[(size_t)e*288 + h];
  #pragma unroll
  for (int s=0;s<16;++s)
    a += part[((size_t)(s*8+e)*288 + h)*64 + b];
  h1[((size_t)e*64 + b)*288 + h] = fmaxf(a, 0.f);
}

__global__ __launch_bounds__(TPB) void expert_h2_k(
    const float* __restrict__ h1, const float* __restrict__ ew2,
    const float* __restrict__ eb2, const float* __restrict__ gates,
    float* __restrict__ h2)
{
  int idx = blockIdx.x*TPB + threadIdx.x;
  if (idx >= 8*64*144) return;
  int k = idx % 144;
  int t = idx / 144;
  int b = t % 64;
  int e = t / 64;
  if (gates[(size_t)b*8 + e] == 0.f) return;
  float acc = eb2[(size_t)e*144 + k];
  const float* h = h1 + ((size_t)e*64 + b)*288;
  const float* w = ew2 + (size_t)e*288*144 + k;
  for (int d=0; d<288; ++d)
    acc = fmaf(h[d], w[(size_t)d*144], acc);
  h2[idx] = fmaxf(acc, 0.f);
}

__global__ __launch_bounds__(TPB) void expert_out_k(
    const float* __restrict__ h2, const float* __restrict__ ew3,
    const float* __restrict__ eb3, const float* __restrict__ gates,
    float* __restrict__ out)
{
  int idx = blockIdx.x*TPB + threadIdx.x;
  if (idx >= 64*1000) return;
  int o = idx % 1000;
  int b = idx / 1000;
  float acc = 0.f;
  const float* gr = gates + (size_t)b*8;
  for (int e=0;e<8;++e){
    float ge = gr[e];
    if (ge == 0.f) continue;
    float a = eb3[(size_t)e*1000 + o];
    const float* h = h2 + ((size_t)e*64 + b)*144;
    const float* w = ew3 + (size_t)e*144*1000 + o;
    for (int k=0;k<144;++k)
      a = fmaf(h[k], w[(size_t)k*1000], a);
    acc = fmaf(ge, a, acc);
  }
  out[idx] = acc;
}

static inline int nblk(long long n){ return (int)((n + TPB - 1) / TPB); }

extern "C" void kernel_launch(void* const* d_in, const int* in_sizes, int n_in,
                              void* d_out, int out_size, void* d_ws, size_t ws_size,
                              hipStream_t stream)
{
  const float* x   = (const float*)d_in[0];
  const float* c1w = (const float*)d_in[1];  const float* c1b = (const float*)d_in[2];
  const float* c2w = (const float*)d_in[3];  const float* c2b = (const float*)d_in[4];
  const float* c3w = (const float*)d_in[5];  const float* c3b = (const float*)d_in[6];
  const float* c4w = (const float*)d_in[7];  const float* c4b = (const float*)d_in[8];
  const float* c5w = (const float*)d_in[9];  const float* c5b = (const float*)d_in[10];
  const float* gw1 = (const float*)d_in[11]; const float* gb1 = (const float*)d_in[12];
  const float* gw2 = (const float*)d_in[13]; const float* gb2 = (const float*)d_in[14];
  const float* ew1 = (const float*)d_in[15]; const float* eb1 = (const float*)d_in[16];
  const float* ew2 = (const float*)d_in[17]; const float* eb2 = (const float*)d_in[18];
  const float* ew3 = (const float*)d_in[19]; const float* eb3 = (const float*)d_in[20];
  float* out = (float*)d_out;

  float* W = (float*)d_ws;
  short* X3H = (short*)W;
  short* X3L = X3H + 8957952;
  short* X5H = (short*)W;
  short* X5L = X5H + 4153344;
  short* X7H = (short*)W;
  short* X7L = X7H + 2768896;
  float* feat  = W + 5000000;
  short* FBH   = (short*)(W + 5600000);
  short* FBL   = (short*)(W + 5900000);
  float* part  = W + 6300000;
  short* WH2 = (short*)(W +  9000000);
  short* WL2 = WH2 + 307200;
  short* WH3 = (short*)(W +  9320000);
  short* WL3 = WH3 + 663552;
  short* WH4 = (short*)(W + 10000000);
  short* WL4 = WH4 + 884736;
  short* WH5 = (short*)(W + 10900000);
  short* WL5 = WH5 + 589824;
  float* GT1 = W + 11500000;
  short* X2H = (short*)(W + 12390400);
  short* X2L = X2H + 2985984;
  short* X4H = (short*)(W + 12390400);
  short* X4L = X4H + 2076672;
  short* X6H = (short*)(W + 12390400);
  short* X6L = X6H + 2768896;
  float* gates = W + 14000000;
  float* h1    = gates + 512;
  float* h2    = h1 + 147456;
  float* gbuf  = h2 + 73728;
  short* WH1 = (short*)(W + 15400000);
  short* WL1 = WH1 + 36864;
  (void)ws_size; (void)in_sizes; (void)n_in; (void)out_size;

  wsplit1_k<<<nblk(64LL*576), TPB, 0, stream>>>(c1w, WH1, WL1);
  conv1p_k<<<dim3(27,64,2), 256, 0, stream>>>(x, WH1, WL1, c1b, X2H, X2L);
  wsplit_k<<<nblk(25LL*192*64),  TPB, 0, stream>>>(c2w, WH2, WL2,  64, 192, 25, 25*192*64);
  wsplit_k<<<nblk(9LL*384*192),  TPB, 0, stream>>>(c3w, WH3, WL3, 192, 384,  9, 9*384*192);
  wsplit_k<<<nblk(9LL*256*384),  TPB, 0, stream>>>(c4w, WH4, WL4, 384, 256,  9, 9*256*384);
  wsplit_k<<<nblk(9LL*256*256),  TPB, 0, stream>>>(c5w, WH5, WL5, 256, 256,  9, 9*256*256);
  wtrans_k<<<nblk(72LL*9216),    TPB, 0, stream>>>(gw1, GT1, 72, 9216);

  // conv2 v4: 128-thread blocks, oc halves across grid z
  conv2m_k<<<dim3(9,64,2), 128, 0, stream>>>(X2H, X2L, WH2, WL2, c2b, X3H, X3L);
  pool2_k<<<nblk(64LL*169*192), TPB, 0, stream>>>(X3H, X3L, X4H, X4L);
  conv3m_k<192,384><<<dim3(12,64), 256, 0, stream>>>(X4H, X4L, WH3, WL3, c3b, X5H, X5L);
  conv3m_k<384,256><<<dim3(8,64),  256, 0, stream>>>(X5H, X5L, WH4, WL4, c4b, X6H, X6L);
  conv3m_k<256,256><<<dim3(8,64),  256, 0, stream>>>(X6H, X6L, WH5, WL5, c5b, X7H, X7L);
  pool3_k<<<nblk(64LL*9216), TPB, 0, stream>>>(X7H, X7L, feat);

  gate1_k<<<dim3(64,18), 256, 0, stream>>>(feat, GT1, gb1, gbuf);
  gate2_k<<<64, 128, 0, stream>>>(gbuf, gw2, gb2, gates);

  featsplit_k<<<nblk(589824LL), TPB, 0, stream>>>(feat, FBH, FBL);
  eh1m_k<<<dim3(9,8,16), 256, 0, stream>>>(ew1, FBH, FBL, part);
  eh1_reduce_k<<<nblk(8LL*288*64), TPB, 0, stream>>>(part, eb1, h1);
  expert_h2_k<<<nblk(8LL*64*144), TPB, 0, stream>>>(h1, ew2, eb2, gates, h2);
  expert_out_k<<<nblk(64LL*1000), TPB, 0, stream>>>(h2, ew3, eb3, gates, out);
}

// Round 21
// 501.047 us; speedup vs baseline: 1.0054x; 1.0054x over previous
//
#include <hip/hip_runtime.h>
#include <math.h>

#define TPB 256

typedef short s16x8 __attribute__((ext_vector_type(8)));
typedef short s16x4 __attribute__((ext_vector_type(4)));
typedef float f32x4 __attribute__((ext_vector_type(4)));

__device__ inline void bsplit(float x, short& h, short& l){
  union { float f; unsigned u; } a, hf, rf;
  a.f = x;
  unsigned hu = (a.u + 0x7FFFu + ((a.u >> 16) & 1u)) >> 16;
  h = (short)hu;
  hf.u = hu << 16;
  rf.f = x - hf.f;
  l = (short)((rf.u + 0x7FFFu + ((rf.u >> 16) & 1u)) >> 16);
}
__device__ inline float b2f(short s){
  union { unsigned u; float f; } x;
  x.u = ((unsigned)(unsigned short)s) << 16;
  return x.f;
}

// ==== weight split + MFMA-native reorder ====
__global__ __launch_bounds__(TPB) void wsplit_k(
    const float* __restrict__ w, short* __restrict__ wh, short* __restrict__ wl,
    int C, int O, int ntap, int total)
{
  int idx = blockIdx.x*TPB + threadIdx.x;
  if (idx >= total) return;
  int c   = idx % C;
  int t2  = idx / C;
  int oc  = t2 % O;
  int tap = t2 / O;
  float x = w[((size_t)oc*C + c)*ntap + tap];
  short h, l; bsplit(x, h, l);
  int tile = oc >> 4, ln = oc & 15;
  int S    = ntap*(C >> 5);
  int sl   = tap*(C >> 5) + (c >> 5);
  int lg   = (c >> 3) & 3, j = c & 7;
  size_t dst = (((size_t)tile*S + sl)*64 + lg*16 + ln)*8 + j;
  wh[dst] = h; wl[dst] = l;
}

__global__ __launch_bounds__(TPB) void wsplit1_k(
    const float* __restrict__ w, short* __restrict__ wh, short* __restrict__ wl)
{
  int idx = blockIdx.x*TPB + threadIdx.x;
  if (idx >= 64*576) return;
  int k  = idx % 576;
  int oc = idx / 576;
  int g  = k >> 4, kw = k & 15;
  int c  = g / 12, kh = g % 12;
  float x = 0.f;
  if (kh < 11 && kw < 11)
    x = w[((size_t)oc*3 + c)*121 + kh*11 + kw];
  short h, l; bsplit(x, h, l);
  int m = oc >> 4, ln = oc & 15;
  int s = k >> 5, r = k & 31;
  int lg = r >> 3, j = r & 7;
  size_t dst = (((size_t)m*18 + s)*64 + lg*16 + ln)*8 + j;
  wh[dst] = h; wl[dst] = l;
}

__global__ __launch_bounds__(TPB) void wtrans_k(
    const float* __restrict__ w, float* __restrict__ wT, int K, int O)
{
  int idx = blockIdx.x*TPB + threadIdx.x;
  if (idx >= K*O) return;
  int oc = idx % O;
  int k  = idx / O;
  wT[idx] = w[(size_t)oc*K + k];
}

// ========= conv1+pool1 fused MFMA v2: ow-split halves for occupancy =========
#define CW1 128
__global__ __launch_bounds__(256, 4) void conv1p_k(
    const float* __restrict__ in, const short* __restrict__ whi,
    const short* __restrict__ wlo, const float* __restrict__ bias,
    short* __restrict__ yh, short* __restrict__ yl)
{
  __shared__ __align__(16) short lds[2][57*CW1 + 176];
  const int tid = threadIdx.x;
  const int r  = blockIdx.x;
  const int b  = blockIdx.y;
  const int hf = blockIdx.z;
  const int wid = tid >> 6;
  const int ntl = wid & 1;
  const int och = wid >> 1;
  const int ln = tid & 15;
  const int lg = (tid & 63) >> 4;
  const int lane = tid & 63;
  const int lw = ntl*16 + ln;
  const int iwbase = hf*112 - 2;

  const float* ip = in + (size_t)b*3*224*224;
  for (int i = tid; i < 57*32; i += 256){
    int plane = i >> 5;
    int p     = i & 31;
    int c = plane / 19, ri = plane % 19;
    int ih = 8*r - 2 + ri;
    int col0 = p*4;
    const float* rowp = (ih >= 0 && ih < 224) ? ip + (size_t)c*50176 + (size_t)ih*224 : nullptr;
    short h[4], l[4];
    #pragma unroll
    for (int j=0;j<4;++j){
      int iw = iwbase + col0 + j;
      float v = (rowp && iw >= 0 && iw < 224) ? rowp[iw] : 0.f;
      bsplit(v, h[j], l[j]);
    }
    s16x4 hv = {h[0],h[1],h[2],h[3]}, lv = {l[0],l[1],l[2],l[3]};
    *reinterpret_cast<s16x4*>(&lds[0][plane*CW1 + col0]) = hv;
    *reinterpret_cast<s16x4*>(&lds[1][plane*CW1 + col0]) = lv;
  }
  __syncthreads();

  f32x4 acc[3][2];
  #pragma unroll
  for (int m=0;m<2;++m){
    const float4 bv = *reinterpret_cast<const float4*>(bias + och*32 + m*16 + lg*4);
    #pragma unroll
    for (int sub=0;sub<3;++sub)
      acc[sub][m] = (f32x4){bv.x, bv.y, bv.z, bv.w};
  }

  s16x8 ah[2], al[2], ahn[2], aln[2];
  #pragma unroll
  for (int m=0;m<2;++m){
    size_t ao = (((size_t)(och*2+m)*18 + 0)*64 + lane)*8;
    ah[m] = *reinterpret_cast<const s16x8*>(whi + ao);
    al[m] = *reinterpret_cast<const s16x8*>(wlo + ao);
  }

  #pragma unroll 1
  for (int s=0; s<18; ++s){
    if (s < 17){
      #pragma unroll
      for (int m=0;m<2;++m){
        size_t ao = (((size_t)(och*2+m)*18 + s + 1)*64 + lane)*8;
        ahn[m] = *reinterpret_cast<const s16x8*>(whi + ao);
        aln[m] = *reinterpret_cast<const s16x8*>(wlo + ao);
      }
    }
    int g  = 2*s + (lg >> 1);
    int c  = g / 12, kh = g % 12;
    int khp = (kh < 11) ? kh : 10;
    #pragma unroll
    for (int sub=0;sub<3;++sub){
      int plane = c*19 + 4*sub + khp;
      int base  = plane*CW1 + lw*4 + (lg & 1)*8;
      s16x4 h0 = *reinterpret_cast<const s16x4*>(&lds[0][base]);
      s16x4 h1 = *reinterpret_cast<const s16x4*>(&lds[0][base+4]);
      s16x4 l0 = *reinterpret_cast<const s16x4*>(&lds[1][base]);
      s16x4 l1 = *reinterpret_cast<const s16x4*>(&lds[1][base+4]);
      s16x8 bh = __builtin_shufflevector(h0, h1, 0,1,2,3,4,5,6,7);
      s16x8 bl = __builtin_shufflevector(l0, l1, 0,1,2,3,4,5,6,7);
      #pragma unroll
      for (int m=0;m<2;++m){
        acc[sub][m] = __builtin_amdgcn_mfma_f32_16x16x32_bf16(al[m], bh, acc[sub][m], 0,0,0);
        acc[sub][m] = __builtin_amdgcn_mfma_f32_16x16x32_bf16(ah[m], bl, acc[sub][m], 0,0,0);
        acc[sub][m] = __builtin_amdgcn_mfma_f32_16x16x32_bf16(ah[m], bh, acc[sub][m], 0,0,0);
      }
    }
    #pragma unroll
    for (int m=0;m<2;++m){ ah[m] = ahn[m]; al[m] = aln[m]; }
  }

  __syncthreads();
  float* convbuf = (float*)&lds[0][0];
  #pragma unroll
  for (int sub=0;sub<3;++sub)
    #pragma unroll
    for (int m=0;m<2;++m)
      #pragma unroll
      for (int rr=0;rr<4;++rr){
        int oc = och*32 + m*16 + lg*4 + rr;
        convbuf[(sub*36 + lw)*65 + oc] = fmaxf(acc[sub][m][rr], 0.f);
      }
  __syncthreads();

  const int npw = hf ? 13 : 14;
  for (int i = tid; i < npw*64; i += 256){
    int pwl = i >> 6, c = i & 63;
    float m = -INFINITY;
    #pragma unroll
    for (int sub=0;sub<3;++sub)
      #pragma unroll
      for (int j=0;j<3;++j)
        m = fmaxf(m, convbuf[(sub*36 + 2*pwl + j)*65 + c]);
    short h, l; bsplit(m, h, l);
    int pw = hf*14 + pwl;
    size_t o = ((size_t)b*729 + r*27 + pw)*64 + c;
    yh[o] = h; yl[o] = l;
  }
}

// ============== conv2 MFMA v3 (reverted from v4): 256 thr, 4 waves ==============
__global__ __launch_bounds__(256, 3) void conv2m_k(
    const short* __restrict__ xh, const short* __restrict__ xl,
    const short* __restrict__ whi, const short* __restrict__ wlo,
    const float* __restrict__ bias, short* __restrict__ yh, short* __restrict__ yl)
{
  __shared__ __align__(16) short lds[2][217*40];
  const int tid = threadIdx.x;
  const int rg  = blockIdx.x;
  const int b   = blockIdx.y;
  const int wid = tid >> 6;
  const int ln  = tid & 15;
  const int lg  = (tid & 63) >> 4;
  const int lane = tid & 63;
  const int oc0 = wid*48;
  const int r0  = rg*3;

  int sb[6], nn[6];
  #pragma unroll
  for (int t=0;t<6;++t){
    int n = t*16 + ln;
    nn[t] = n;
    int ohl = n / 27, ow = n % 27;
    sb[t] = (n < 81) ? (ohl*31 + ow) : 0;
  }

  f32x4 acc[3][6];
  #pragma unroll
  for (int m=0;m<3;++m){
    const float4 bv = *reinterpret_cast<const float4*>(bias + oc0 + m*16 + lg*4);
    #pragma unroll
    for (int t=0;t<6;++t) acc[m][t] = (f32x4){bv.x, bv.y, bv.z, bv.w};
  }

  #pragma unroll 1
  for (int c0=0; c0<64; c0+=32){
    __syncthreads();
    for (int i = tid; i < 217*4; i += 256){
      int sp = i >> 2, v = i & 3;
      int pr = sp/31, pc = sp%31;
      int ih = r0 - 2 + pr, iw = pc - 2;
      s16x8 hv = {0,0,0,0,0,0,0,0}, lv = {0,0,0,0,0,0,0,0};
      if (ih >= 0 && ih < 27 && iw >= 0 && iw < 27){
        size_t o = ((size_t)b*729 + ih*27 + iw)*64 + c0 + v*8;
        hv = *reinterpret_cast<const s16x8*>(xh + o);
        lv = *reinterpret_cast<const s16x8*>(xl + o);
      }
      *reinterpret_cast<s16x8*>(&lds[0][sp*40 + v*8]) = hv;
      *reinterpret_cast<s16x8*>(&lds[1][sp*40 + v*8]) = lv;
    }
    __syncthreads();

    const size_t tstr = 50*512;
    const size_t abase = ((size_t)(wid*3)*50 + (c0 >> 5))*512 + (size_t)lane*8;
    s16x8 ah0 = *reinterpret_cast<const s16x8*>(whi + abase);
    s16x8 ah1 = *reinterpret_cast<const s16x8*>(whi + abase + tstr);
    s16x8 ah2 = *reinterpret_cast<const s16x8*>(whi + abase + 2*tstr);
    s16x8 al0 = *reinterpret_cast<const s16x8*>(wlo + abase);
    s16x8 al1 = *reinterpret_cast<const s16x8*>(wlo + abase + tstr);
    s16x8 al2 = *reinterpret_cast<const s16x8*>(wlo + abase + 2*tstr);

    #pragma unroll 1
    for (int tap=0; tap<25; ++tap){
      s16x8 nh0=ah0, nh1=ah1, nh2=ah2, nl0=al0, nl1=al1, nl2=al2;
      if (tap < 24){
        size_t ao = abase + (size_t)(tap+1)*2*512;
        nh0 = *reinterpret_cast<const s16x8*>(whi + ao);
        nh1 = *reinterpret_cast<const s16x8*>(whi + ao + tstr);
        nh2 = *reinterpret_cast<const s16x8*>(whi + ao + 2*tstr);
        nl0 = *reinterpret_cast<const s16x8*>(wlo + ao);
        nl1 = *reinterpret_cast<const s16x8*>(wlo + ao + tstr);
        nl2 = *reinterpret_cast<const s16x8*>(wlo + ao + 2*tstr);
      }
      const int toff = (tap/5)*31 + (tap%5);
      #pragma unroll
      for (int t=0;t<6;++t){
        int off = (sb[t] + toff)*40 + lg*8;
        s16x8 bh = *reinterpret_cast<const s16x8*>(&lds[0][off]);
        s16x8 bl = *reinterpret_cast<const s16x8*>(&lds[1][off]);
        acc[0][t] = __builtin_amdgcn_mfma_f32_16x16x32_bf16(al0, bh, acc[0][t], 0,0,0);
        acc[0][t] = __builtin_amdgcn_mfma_f32_16x16x32_bf16(ah0, bl, acc[0][t], 0,0,0);
        acc[0][t] = __builtin_amdgcn_mfma_f32_16x16x32_bf16(ah0, bh, acc[0][t], 0,0,0);
        acc[1][t] = __builtin_amdgcn_mfma_f32_16x16x32_bf16(al1, bh, acc[1][t], 0,0,0);
        acc[1][t] = __builtin_amdgcn_mfma_f32_16x16x32_bf16(ah1, bl, acc[1][t], 0,0,0);
        acc[1][t] = __builtin_amdgcn_mfma_f32_16x16x32_bf16(ah1, bh, acc[1][t], 0,0,0);
        acc[2][t] = __builtin_amdgcn_mfma_f32_16x16x32_bf16(al2, bh, acc[2][t], 0,0,0);
        acc[2][t] = __builtin_amdgcn_mfma_f32_16x16x32_bf16(ah2, bl, acc[2][t], 0,0,0);
        acc[2][t] = __builtin_amdgcn_mfma_f32_16x16x32_bf16(ah2, bh, acc[2][t], 0,0,0);
      }
      ah0=nh0; ah1=nh1; ah2=nh2; al0=nl0; al1=nl1; al2=nl2;
    }
  }

  #pragma unroll
  for (int m=0;m<3;++m)
    #pragma unroll
    for (int t=0;t<6;++t){
      if (nn[t] < 81){
        int gsp = r0*27 + nn[t];
        size_t base = ((size_t)b*729 + gsp)*192 + oc0 + m*16 + lg*4;
        short h[4], l[4];
        #pragma unroll
        for (int r=0;r<4;++r) bsplit(fmaxf(acc[m][t][r], 0.f), h[r], l[r]);
        s16x4 hv = {h[0],h[1],h[2],h[3]}, lv = {l[0],l[1],l[2],l[3]};
        *reinterpret_cast<s16x4*>(yh + base) = hv;
        *reinterpret_cast<s16x4*>(yl + base) = lv;
      }
    }
}

// ---- pool2: X3[729][192] split -> X4[169][192] split ----
__global__ __launch_bounds__(TPB) void pool2_k(
    const short* __restrict__ xh, const short* __restrict__ xl,
    short* __restrict__ yh, short* __restrict__ yl)
{
  int i = blockIdx.x*TPB + threadIdx.x;
  if (i >= 64*169*192) return;
  int c = i % 192;
  int t = i / 192;
  int sp = t % 169;
  int b = t / 169;
  int r = sp/13, cc = sp%13;
  const short* ph = xh + (size_t)b*729*192 + c;
  const short* pl = xl + (size_t)b*729*192 + c;
  float m = -INFINITY;
  #pragma unroll
  for (int di=0;di<3;++di)
    #pragma unroll
    for (int dj=0;dj<3;++dj){
      size_t s = (size_t)((2*r+di)*27 + 2*cc+dj)*192;
      m = fmaxf(m, b2f(ph[s]) + b2f(pl[s]));
    }
  short h, l; bsplit(m, h, l);
  yh[i] = h; yl[i] = l;
}

// ============== conv3/4/5 MFMA; in: split ch-minor [169][C]; out: [169][O] =====
template<int C,int O>
__global__ __launch_bounds__(256, 3) void conv3m_k(
    const short* __restrict__ xh, const short* __restrict__ xl,
    const short* __restrict__ whi, const short* __restrict__ wlo,
    const float* __restrict__ bias, short* __restrict__ yh, short* __restrict__ yl)
{
  __shared__ __align__(16) short lds[2][225*40];
  const int tid = threadIdx.x;
  const int b   = blockIdx.y;
  const int wid = tid >> 6;
  const int ln  = tid & 15;
  const int lg  = (tid & 63) >> 4;
  const int lane = tid & 63;
  const int tileIdx = blockIdx.x*2 + (wid & 1);
  const int oc0 = tileIdx*16;
  const int ng  = wid >> 1;
  const int tbase  = ng ? 6 : 0;
  const int ntiles = ng ? 5 : 6;
  const int S3 = 9*(C/32);

  int sb[6], nn[6];
  #pragma unroll
  for (int t=0;t<6;++t){
    int n = (tbase + t)*16 + ln;
    nn[t] = n;
    int oh = n / 13, ow = n % 13;
    sb[t] = (n < 169) ? (oh*15 + ow) : 0;
  }

  f32x4 acc[6];
  const float4 bv = *reinterpret_cast<const float4*>(bias + oc0 + lg*4);
  #pragma unroll
  for (int t=0;t<6;++t) acc[t] = (f32x4){bv.x, bv.y, bv.z, bv.w};

  #pragma unroll 1
  for (int c0=0; c0<C; c0+=32){
    __syncthreads();
    for (int i = tid; i < 225*4; i += 256){
      int sp = i >> 2, v = i & 3;
      int r = sp/15, cc = sp%15;
      s16x8 hv = {0,0,0,0,0,0,0,0}, lv = {0,0,0,0,0,0,0,0};
      if (r >= 1 && r <= 13 && cc >= 1 && cc <= 13){
        size_t o = ((size_t)b*169 + (r-1)*13 + (cc-1))*C + c0 + v*8;
        hv = *reinterpret_cast<const s16x8*>(xh + o);
        lv = *reinterpret_cast<const s16x8*>(xl + o);
      }
      *reinterpret_cast<s16x8*>(&lds[0][sp*40 + v*8]) = hv;
      *reinterpret_cast<s16x8*>(&lds[1][sp*40 + v*8]) = lv;
    }
    __syncthreads();

    const size_t tb = (size_t)tileIdx*S3 + (c0 >> 5);
    s16x8 ah = *reinterpret_cast<const s16x8*>(whi + (tb*64 + lane)*8);
    s16x8 al = *reinterpret_cast<const s16x8*>(wlo + (tb*64 + lane)*8);
    #pragma unroll 1
    for (int tap=0; tap<9; ++tap){
      s16x8 ahn = ah, aln = al;
      if (tap < 8){
        size_t ao = ((tb + (size_t)(tap+1)*(C/32))*64 + lane)*8;
        ahn = *reinterpret_cast<const s16x8*>(whi + ao);
        aln = *reinterpret_cast<const s16x8*>(wlo + ao);
      }
      const int toff = (tap/3)*15 + (tap%3);
      #pragma unroll
      for (int t=0;t<6;++t){
        if (t < ntiles){
          int off = (sb[t] + toff)*40 + lg*8;
          s16x8 bh = *reinterpret_cast<const s16x8*>(&lds[0][off]);
          s16x8 bl = *reinterpret_cast<const s16x8*>(&lds[1][off]);
          acc[t] = __builtin_amdgcn_mfma_f32_16x16x32_bf16(al, bh, acc[t], 0,0,0);
          acc[t] = __builtin_amdgcn_mfma_f32_16x16x32_bf16(ah, bl, acc[t], 0,0,0);
          acc[t] = __builtin_amdgcn_mfma_f32_16x16x32_bf16(ah, bh, acc[t], 0,0,0);
        }
      }
      ah = ahn; al = aln;
    }
  }

  #pragma unroll
  for (int t=0;t<6;++t){
    if (t < ntiles && nn[t] < 169){
      size_t base = ((size_t)b*169 + nn[t])*O + oc0 + lg*4;
      short h[4], l[4];
      #pragma unroll
      for (int r=0;r<4;++r) bsplit(fmaxf(acc[t][r], 0.f), h[r], l[r]);
      s16x4 hv = {h[0],h[1],h[2],h[3]}, lv = {l[0],l[1],l[2],l[3]};
      *reinterpret_cast<s16x4*>(yh + base) = hv;
      *reinterpret_cast<s16x4*>(yl + base) = lv;
    }
  }
}

// ---- pool3: X7[169][256] split -> feat[b][9216] f32 (d = c*36 + sp) ----
__global__ __launch_bounds__(TPB) void pool3_k(
    const short* __restrict__ xh, const short* __restrict__ xl,
    float* __restrict__ feat)
{
  int i = blockIdx.x*TPB + threadIdx.x;
  if (i >= 64*9216) return;
  int d = i % 9216;
  int b = i / 9216;
  int c = d / 36;
  int sp = d % 36;
  int r = sp/6, cc = sp%6;
  const short* ph = xh + (size_t)b*169*256 + c;
  const short* pl = xl + (size_t)b*169*256 + c;
  float m = -INFINITY;
  #pragma unroll
  for (int di=0;di<3;++di)
    #pragma unroll
    for (int dj=0;dj<3;++dj){
      size_t s = (size_t)((2*r+di)*13 + 2*cc+dj)*256;
      m = fmaxf(m, b2f(ph[s]) + b2f(pl[s]));
    }
  feat[i] = m;
}

// ---- featsplit: feat[b][9216] -> featBT B-native [288 s][4 nt][64 lane][8 j] ----
__global__ __launch_bounds__(TPB) void featsplit_k(
    const float* __restrict__ feat, short* __restrict__ fbh, short* __restrict__ fbl)
{
  int idx = blockIdx.x*TPB + threadIdx.x;
  if (idx >= 589824) return;
  int j = idx & 7;
  int lane = (idx >> 3) & 63;
  int nt = (idx >> 9) & 3;
  int s = idx >> 11;
  int b = nt*16 + (lane & 15);
  int d = s*32 + (lane >> 4)*8 + j;
  short h, l; bsplit(feat[(size_t)b*9216 + d], h, l);
  fbh[idx] = h; fbl[idx] = l;
}

// ---------------- gate ----------------
__global__ __launch_bounds__(256) void gate1_k(
    const float* __restrict__ feat, const float* __restrict__ gw1T,
    const float* __restrict__ gb1, float* __restrict__ g)
{
  const int b    = blockIdx.x;
  const int h    = blockIdx.y*4 + (threadIdx.x >> 6);
  const int lane = threadIdx.x & 63;
  const float* f = feat + (size_t)b*9216;
  const float* w = gw1T + (size_t)h*9216;
  float s = 0.f;
  #pragma unroll
  for (int it=0; it<36; ++it){
    int d = it*256 + lane*4;
    float4 fv = *reinterpret_cast<const float4*>(f + d);
    float4 wv = *reinterpret_cast<const float4*>(w + d);
    s = fmaf(fv.x, wv.x, s);
    s = fmaf(fv.y, wv.y, s);
    s = fmaf(fv.z, wv.z, s);
    s = fmaf(fv.w, wv.w, s);
  }
  #pragma unroll
  for (int off=32; off; off>>=1) s += __shfl_down(s, off, 64);
  if (lane == 0) g[(size_t)b*72 + h] = fmaxf(s + gb1[h], 0.f);
}

__global__ __launch_bounds__(128) void gate2_k(
    const float* __restrict__ g, const float* __restrict__ gw2,
    const float* __restrict__ gb2, float* __restrict__ gates)
{
  const int b = blockIdx.x;
  const int tid = threadIdx.x;
  __shared__ float gs[72];
  __shared__ float logits[8];
  if (tid < 72) gs[tid] = g[(size_t)b*72 + tid];
  __syncthreads();
  if (tid < 8) {
    float acc = gb2[tid];
    for (int j=0;j<72;++j)
      acc = fmaf(gs[j], gw2[(size_t)j*8 + tid], acc);
    logits[tid] = acc;
  }
  __syncthreads();
  if (tid == 0) {
    int i1 = 0; float v1 = logits[0];
    for (int e=1;e<8;++e) if (logits[e] > v1) { v1 = logits[e]; i1 = e; }
    int i2 = -1; float v2 = -INFINITY;
    for (int e=0;e<8;++e) { if (e==i1) continue; if (logits[e] > v2) { v2 = logits[e]; i2 = e; } }
    float z  = expf(v2 - v1);
    float w1 = 1.f / (1.f + z);
    float w2 = z   / (1.f + z);
    float* gr = gates + (size_t)b*8;
    for (int e=0;e<8;++e) gr[e] = 0.f;
    gr[i1] = w1;
    gr[i2] = w2;
  }
}

// ========== expert h1 MFMA streaming GEMM ==========
__global__ __launch_bounds__(256, 4) void eh1m_k(
    const float* __restrict__ ew1, const short* __restrict__ fbh,
    const short* __restrict__ fbl, float* __restrict__ part)
{
  __shared__ __align__(16) short wh_l[32*88];
  __shared__ __align__(16) short wl_l[32*88];
  const int m2 = blockIdx.x;
  const int e  = blockIdx.y;
  const int ks = blockIdx.z;
  const int tid = threadIdx.x;
  const int nt = tid >> 6;
  const int ln = tid & 15;
  const int lg = (tid & 63) >> 4;
  const int lane = tid & 63;

  f32x4 acc[2] = {(f32x4){0.f,0.f,0.f,0.f},(f32x4){0.f,0.f,0.f,0.f}};

  const float* wsrc = ew1 + (size_t)e*9216*288 + (size_t)m2*32;
  const int d0 = ks*576;

  #pragma unroll 1
  for (int st=0; st<9; ++st){
    __syncthreads();
    {
      int drow = tid >> 2;
      int h0 = (tid & 3)*8;
      const float* src = wsrc + (size_t)(d0 + st*64 + drow)*288 + h0;
      float4 v0 = *reinterpret_cast<const float4*>(src);
      float4 v1 = *reinterpret_cast<const float4*>(src+4);
      float vv[8] = {v0.x,v0.y,v0.z,v0.w,v1.x,v1.y,v1.z,v1.w};
      #pragma unroll
      for (int k=0;k<8;++k){
        short h, l; bsplit(vv[k], h, l);
        wh_l[(h0+k)*88 + drow] = h;
        wl_l[(h0+k)*88 + drow] = l;
      }
    }
    __syncthreads();
    int sg = (d0 + st*64) >> 5;
    #pragma unroll
    for (int sl=0; sl<2; ++sl){
      size_t bo = ((size_t)(sg+sl)*4 + nt)*512 + (size_t)lane*8;
      s16x8 bh = *reinterpret_cast<const s16x8*>(fbh + bo);
      s16x8 bl = *reinterpret_cast<const s16x8*>(fbl + bo);
      #pragma unroll
      for (int m=0;m<2;++m){
        int ao = (m*16 + ln)*88 + sl*32 + lg*8;
        s16x8 ah = *reinterpret_cast<const s16x8*>(&wh_l[ao]);
        s16x8 al = *reinterpret_cast<const s16x8*>(&wl_l[ao]);
        acc[m] = __builtin_amdgcn_mfma_f32_16x16x32_bf16(al, bh, acc[m], 0,0,0);
        acc[m] = __builtin_amdgcn_mfma_f32_16x16x32_bf16(ah, bl, acc[m], 0,0,0);
        acc[m] = __builtin_amdgcn_mfma_f32_16x16x32_bf16(ah, bh, acc[m], 0,0,0);
      }
    }
  }
  #pragma unroll
  for (int m=0;m<2;++m){
    int h = m2*32 + m*16 + lg*4;
    int b = nt*16 + ln;
    float* pp = part + ((size_t)(ks*8+e)*288 + h)*64 + b;
    #pragma unroll
    for (int r=0;r<4;++r)
      pp[(size_t)r*64] = acc[m][r];
  }
}

__global__ __launch_bounds__(TPB) void eh1_reduce_k(
    const float* __restrict__ part, const float* __restrict__ eb1,
    float* __restrict__ h1)
{
  int idx = blockIdx.x*TPB + threadIdx.x;
  if (idx >= 8*288*64) return;
  int b = idx & 63;
  int h = (idx >> 6) % 288;
  int e = idx / (64*288);
  float a = eb1[(size_t)e*288 + h];
  #pragma unroll
  for (int s=0;s<16;++s)
    a += part[((size_t)(s*8+e)*288 + h)*64 + b];
  h1[((size_t)e*64 + b)*288 + h] = fmaxf(a, 0.f);
}

__global__ __launch_bounds__(TPB) void expert_h2_k(
    const float* __restrict__ h1, const float* __restrict__ ew2,
    const float* __restrict__ eb2, const float* __restrict__ gates,
    float* __restrict__ h2)
{
  int idx = blockIdx.x*TPB + threadIdx.x;
  if (idx >= 8*64*144) return;
  int k = idx % 144;
  int t = idx / 144;
  int b = t % 64;
  int e = t / 64;
  if (gates[(size_t)b*8 + e] == 0.f) return;
  float acc = eb2[(size_t)e*144 + k];
  const float* h = h1 + ((size_t)e*64 + b)*288;
  const float* w = ew2 + (size_t)e*288*144 + k;
  for (int d=0; d<288; ++d)
    acc = fmaf(h[d], w[(size_t)d*144], acc);
  h2[idx] = fmaxf(acc, 0.f);
}

__global__ __launch_bounds__(TPB) void expert_out_k(
    const float* __restrict__ h2, const float* __restrict__ ew3,
    const float* __restrict__ eb3, const float* __restrict__ gates,
    float* __restrict__ out)
{
  int idx = blockIdx.x*TPB + threadIdx.x;
  if (idx >= 64*1000) return;
  int o = idx % 1000;
  int b = idx / 1000;
  float acc = 0.f;
  const float* gr = gates + (size_t)b*8;
  for (int e=0;e<8;++e){
    float ge = gr[e];
    if (ge == 0.f) continue;
    float a = eb3[(size_t)e*1000 + o];
    const float* h = h2 + ((size_t)e*64 + b)*144;
    const float* w = ew3 + (size_t)e*144*1000 + o;
    for (int k=0;k<144;++k)
      a = fmaf(h[k], w[(size_t)k*1000], a);
    acc = fmaf(ge, a, acc);
  }
  out[idx] = acc;
}

static inline int nblk(long long n){ return (int)((n + TPB - 1) / TPB); }

extern "C" void kernel_launch(void* const* d_in, const int* in_sizes, int n_in,
                              void* d_out, int out_size, void* d_ws, size_t ws_size,
                              hipStream_t stream)
{
  const float* x   = (const float*)d_in[0];
  const float* c1w = (const float*)d_in[1];  const float* c1b = (const float*)d_in[2];
  const float* c2w = (const float*)d_in[3];  const float* c2b = (const float*)d_in[4];
  const float* c3w = (const float*)d_in[5];  const float* c3b = (const float*)d_in[6];
  const float* c4w = (const float*)d_in[7];  const float* c4b = (const float*)d_in[8];
  const float* c5w = (const float*)d_in[9];  const float* c5b = (const float*)d_in[10];
  const float* gw1 = (const float*)d_in[11]; const float* gb1 = (const float*)d_in[12];
  const float* gw2 = (const float*)d_in[13]; const float* gb2 = (const float*)d_in[14];
  const float* ew1 = (const float*)d_in[15]; const float* eb1 = (const float*)d_in[16];
  const float* ew2 = (const float*)d_in[17]; const float* eb2 = (const float*)d_in[18];
  const float* ew3 = (const float*)d_in[19]; const float* eb3 = (const float*)d_in[20];
  float* out = (float*)d_out;

  float* W = (float*)d_ws;
  short* X3H = (short*)W;
  short* X3L = X3H + 8957952;
  short* X5H = (short*)W;
  short* X5L = X5H + 4153344;
  short* X7H = (short*)W;
  short* X7L = X7H + 2768896;
  float* feat  = W + 5000000;
  short* FBH   = (short*)(W + 5600000);
  short* FBL   = (short*)(W + 5900000);
  float* part  = W + 6300000;
  short* WH2 = (short*)(W +  9000000);
  short* WL2 = WH2 + 307200;
  short* WH3 = (short*)(W +  9320000);
  short* WL3 = WH3 + 663552;
  short* WH4 = (short*)(W + 10000000);
  short* WL4 = WH4 + 884736;
  short* WH5 = (short*)(W + 10900000);
  short* WL5 = WH5 + 589824;
  float* GT1 = W + 11500000;
  short* X2H = (short*)(W + 12390400);
  short* X2L = X2H + 2985984;
  short* X4H = (short*)(W + 12390400);
  short* X4L = X4H + 2076672;
  short* X6H = (short*)(W + 12390400);
  short* X6L = X6H + 2768896;
  float* gates = W + 14000000;
  float* h1    = gates + 512;
  float* h2    = h1 + 147456;
  float* gbuf  = h2 + 73728;
  short* WH1 = (short*)(W + 15400000);
  short* WL1 = WH1 + 36864;
  (void)ws_size; (void)in_sizes; (void)n_in; (void)out_size;

  wsplit1_k<<<nblk(64LL*576), TPB, 0, stream>>>(c1w, WH1, WL1);
  conv1p_k<<<dim3(27,64,2), 256, 0, stream>>>(x, WH1, WL1, c1b, X2H, X2L);
  wsplit_k<<<nblk(25LL*192*64),  TPB, 0, stream>>>(c2w, WH2, WL2,  64, 192, 25, 25*192*64);
  wsplit_k<<<nblk(9LL*384*192),  TPB, 0, stream>>>(c3w, WH3, WL3, 192, 384,  9, 9*384*192);
  wsplit_k<<<nblk(9LL*256*384),  TPB, 0, stream>>>(c4w, WH4, WL4, 384, 256,  9, 9*256*384);
  wsplit_k<<<nblk(9LL*256*256),  TPB, 0, stream>>>(c5w, WH5, WL5, 256, 256,  9, 9*256*256);
  wtrans_k<<<nblk(72LL*9216),    TPB, 0, stream>>>(gw1, GT1, 72, 9216);

  // conv2 v3 (reverted): 256-thread blocks, grid (9,64)
  conv2m_k<<<dim3(9,64), 256, 0, stream>>>(X2H, X2L, WH2, WL2, c2b, X3H, X3L);
  pool2_k<<<nblk(64LL*169*192), TPB, 0, stream>>>(X3H, X3L, X4H, X4L);
  conv3m_k<192,384><<<dim3(12,64), 256, 0, stream>>>(X4H, X4L, WH3, WL3, c3b, X5H, X5L);
  conv3m_k<384,256><<<dim3(8,64),  256, 0, stream>>>(X5H, X5L, WH4, WL4, c4b, X6H, X6L);
  conv3m_k<256,256><<<dim3(8,64),  256, 0, stream>>>(X6H, X6L, WH5, WL5, c5b, X7H, X7L);
  pool3_k<<<nblk(64LL*9216), TPB, 0, stream>>>(X7H, X7L, feat);

  gate1_k<<<dim3(64,18), 256, 0, stream>>>(feat, GT1, gb1, gbuf);
  gate2_k<<<64, 128, 0, stream>>>(gbuf, gw2, gb2, gates);

  featsplit_k<<<nblk(589824LL), TPB, 0, stream>>>(feat, FBH, FBL);
  eh1m_k<<<dim3(9,8,16), 256, 0, stream>>>(ew1, FBH, FBL, part);
  eh1_reduce_k<<<nblk(8LL*288*64), TPB, 0, stream>>>(part, eb1, h1);
  expert_h2_k<<<nblk(8LL*64*144), TPB, 0, stream>>>(h1, ew2, eb2, gates, h2);
  expert_out_k<<<nblk(64LL*1000), TPB, 0, stream>>>(h2, ew3, eb3, gates, out);
}